// Round 14
// baseline (327.074 us; speedup 1.0000x reference)
//
#include <hip/hip_runtime.h>

#define NV   20000
#define MAXN 16
#define VPB  4
#define NBLK 5000

// ---------------------------------------------------------------------------
// Mask dtype detection (bool may arrive as int32 / byte / float32).
// ---------------------------------------------------------------------------
__global__ void detect_mask_kind(const unsigned int* __restrict__ m,
                                 int* __restrict__ flag) {
    if (threadIdx.x == 0 && blockIdx.x == 0) {
        int allint = 1, allflt = 1;
        #pragma unroll 8
        for (int k = 0; k < 64; ++k) {
            unsigned w = m[k];
            if (!(w == 0u || w == 1u)) allint = 0;
            if (!(w == 0u || w == 0x3F800000u)) allflt = 0;
        }
        *flag = allint ? 0 : (allflt ? 2 : 1);
    }
}

// ---------------------------------------------------------------------------
// One-time weight combine: per thread slot t=(c,i), 8 rows of 8
// (WQ, WK, W0, W1o0, W1o1, W2o0, W2o1, W2o2) = 16 float4 contiguous per t.
// ---------------------------------------------------------------------------
__global__ void compute_weights(const float* __restrict__ rr,
                                const float* __restrict__ vb0,
                                const float* __restrict__ vb1,
                                const float* __restrict__ vb2,
                                const float* __restrict__ qc,
                                const float* __restrict__ kc,
                                const float* __restrict__ w0p,
                                const float* __restrict__ w1p,
                                const float* __restrict__ w2p,
                                float4* __restrict__ wt) {
    const int t = threadIdx.x;
    const int c = t & 31;
    const int i = t >> 5;
    float WQr[8], WKr[8], W0r[8], W1r0[8], W1r1[8], W2r0[8], W2r1[8], W2r2[8];
    #pragma unroll
    for (int j = 0; j < 8; ++j) {
        WQr[j] = 0.f; WKr[j] = 0.f; W0r[j] = 0.f; W1r0[j] = 0.f;
        W1r1[j] = 0.f; W2r0[j] = 0.f; W2r1[j] = 0.f; W2r2[j] = 0.f;
    }
    #pragma unroll
    for (int b = 0; b < 8; ++b) {
        const float qcb = qc[c * 8 + b];
        const float kcb = kc[c * 8 + b];
        const float w0b = w0p[c * 8 + b];
        const float w1b = w1p[c * 8 + b];
        const float w2b = w2p[c * 8 + b];
        const float* rrb = rr  + b * 64  + i * 8;
        const float* z0  = vb0 + b * 64  + i * 8;
        const float* z1  = vb1 + b * 128 + i * 8;   // [b][o][i][j]
        const float* z2  = vb2 + b * 192 + i * 8;
        #pragma unroll
        for (int j = 0; j < 8; ++j) {
            const float r = rrb[j];
            WQr[j]  = fmaf(qcb, r, WQr[j]);
            WKr[j]  = fmaf(kcb, r, WKr[j]);
            W0r[j]  = fmaf(w0b, z0[j],       W0r[j]);
            W1r0[j] = fmaf(w1b, z1[j],       W1r0[j]);
            W1r1[j] = fmaf(w1b, z1[64 + j],  W1r1[j]);
            W2r0[j] = fmaf(w2b, z2[j],       W2r0[j]);
            W2r1[j] = fmaf(w2b, z2[64 + j],  W2r1[j]);
            W2r2[j] = fmaf(w2b, z2[128 + j], W2r2[j]);
        }
    }
    float4* o = wt + t * 16;
    o[ 0] = *(const float4*)&WQr[0];  o[ 1] = *(const float4*)&WQr[4];
    o[ 2] = *(const float4*)&WKr[0];  o[ 3] = *(const float4*)&WKr[4];
    o[ 4] = *(const float4*)&W0r[0];  o[ 5] = *(const float4*)&W0r[4];
    o[ 6] = *(const float4*)&W1r0[0]; o[ 7] = *(const float4*)&W1r0[4];
    o[ 8] = *(const float4*)&W1r1[0]; o[ 9] = *(const float4*)&W1r1[4];
    o[10] = *(const float4*)&W2r0[0]; o[11] = *(const float4*)&W2r0[4];
    o[12] = *(const float4*)&W2r1[0]; o[13] = *(const float4*)&W2r1[4];
    o[14] = *(const float4*)&W2r2[0]; o[15] = *(const float4*)&W2r2[4];
}

__device__ __forceinline__ float dot8a(const float* __restrict__ w,
                                       const float* __restrict__ f) {
    float s = w[0] * f[0];
    #pragma unroll
    for (int j = 1; j < 8; ++j) s = fmaf(w[j], f[j], s);
    return s;
}

__device__ __forceinline__ float dot8f4(const float4& a, const float4& b,
                                        const float* __restrict__ f) {
    return fmaf(a.x, f[0], fmaf(a.y, f[1], fmaf(a.z, f[2], fmaf(a.w, f[3],
           fmaf(b.x, f[4], fmaf(b.y, f[5], fmaf(b.z, f[6], b.w * f[7])))))));
}

// R13 + three structural cuts:
//  (a) sqni stage eliminated: Q[n,i] reduces fully within one 32-lane half
//      (c spans the half; kreg=K[i] is thread-local) -> depth-5 shfl, relu,
//      2-lane atomicAdd into sn[n]. 4 barriers -> 3, no zeroing/fixup.
//  (b) VPB=4: W loads + pins once per block (R13 paid them per vertex).
//  (c) neighbor-pair float2 LDS reads (stride-18 even pad, 8B aligned,
//      2-way bank aliasing = free): pass A 128->64 ops, agg 16->8.
__global__ void __launch_bounds__(256, 5)
ge_attn_kernel(const float* __restrict__ x,
               const int*   __restrict__ neighbors,
               const void*  __restrict__ maskp,
               const float* __restrict__ ptm,
               const float* __restrict__ rpu,
               const float4* __restrict__ wt,
               const int*   __restrict__ mflag,
               float*       __restrict__ out) {
    const int t = threadIdx.x;
    const int c = t & 31;   // channel
    const int i = t >> 5;   // rep index (also j-slot in aggregation)
    const int mf = *mflag;

    // f' store: [j][c][n], stride-18 pad (even -> float2-aligned pairs)
    __shared__ float fsh2[8][32][18];  // 18.4KB
    __shared__ float Fsh[8][32][6];    // aggregated features [j][c][k] 6KB
    __shared__ float sn[16];           // sum_i relu(Q+K)
    __shared__ float smask[16];

    // weight rows, pinned once per block (R13: per vertex)
    float WQK[16], WV[48];
    {
        const float4* wp = wt + t * 16;
        #pragma unroll
        for (int r = 0; r < 4; ++r) {
            const float4 q = wp[r];
            WQK[r * 4 + 0] = q.x; WQK[r * 4 + 1] = q.y;
            WQK[r * 4 + 2] = q.z; WQK[r * 4 + 3] = q.w;
        }
        #pragma unroll
        for (int r = 0; r < 12; ++r) {
            const float4 q = wp[r + 4];
            WV[r * 4 + 0] = q.x; WV[r * 4 + 1] = q.y;
            WV[r * 4 + 2] = q.z; WV[r * 4 + 3] = q.w;
        }
        #pragma unroll
        for (int r = 0; r < 16; ++r) asm volatile("" : "+v"(WQK[r]));
        #pragma unroll
        for (int r = 0; r < 48; ++r) asm volatile("" : "+v"(WV[r]));
    }

    for (int vi = 0; vi < VPB; ++vi) {
        const int v  = blockIdx.x * VPB + vi;
        const int vq = v * 16;

        // mask -> LDS; zero sn (both consumed only after B1/B2)
        if (t < 16) {
            int mm;
            if (mf == 0)      mm = (((const int*)maskp)[vq + t] != 0);
            else if (mf == 1) mm = (((const unsigned char*)maskp)[vq + t] != 0);
            else              mm = (((const float*)maskp)[vq + t] != 0.0f);
            smask[t] = mm ? 1.f : 0.f;
        } else if (t < 32) {
            sn[t - 16] = 0.f;
        }

        // ---- phase 1: transport n=2i,2i+1 (mask-scaled) -> fsh2 ----
        #pragma unroll
        for (int sub = 0; sub < 2; ++sub) {
            const int n = 2 * i + sub;
            int mm;
            if (mf == 0)      mm = (((const int*)maskp)[vq + n] != 0);
            else if (mf == 1) mm = (((const unsigned char*)maskp)[vq + n] != 0);
            else              mm = (((const float*)maskp)[vq + n] != 0.0f);
            const float m = mm ? 1.f : 0.f;
            const int nbv = neighbors[vq + n];
            float xn[8];
            {
                const float* xnp = x + (size_t)nbv * 256 + c * 8;
                *(float4*)&xn[0] = *(const float4*)xnp;
                *(float4*)&xn[4] = *(const float4*)(xnp + 4);
            }
            const float4* P4 = (const float4*)(ptm + (size_t)(vq + n) * 64);
            #pragma unroll
            for (int j2 = 0; j2 < 4; ++j2) {
                fsh2[2 * j2    ][c][n] = dot8f4(P4[4 * j2 + 0], P4[4 * j2 + 1], xn) * m;
                fsh2[2 * j2 + 1][c][n] = dot8f4(P4[4 * j2 + 2], P4[4 * j2 + 3], xn) * m;
            }
        }

        // K[i]: in-half-wave reduction, stays in register (all lanes)
        float kreg;
        {
            float xc[8];
            const float* xv = x + (size_t)v * 256 + c * 8;
            *(float4*)&xc[0] = *(const float4*)xv;
            *(float4*)&xc[4] = *(const float4*)(xv + 4);
            float kp = dot8a(&WQK[8], xc);
            kp += __shfl_xor(kp, 1);
            kp += __shfl_xor(kp, 2);
            kp += __shfl_xor(kp, 4);
            kp += __shfl_xor(kp, 8);
            kp += __shfl_xor(kp, 16);
            kreg = kp;
        }

        __syncthreads();   // B1: fsh2, smask, sn=0

        // ---- pass A: full in-half Q[n,i] (2-chain ILP), relu, 2-lane atomic
        #pragma unroll
        for (int n2 = 0; n2 < 8; ++n2) {
            const int n = 2 * n2;
            float2 fj[8];
            #pragma unroll
            for (int j = 0; j < 8; ++j)
                fj[j] = *(const float2*)&fsh2[j][c][n];
            float qa = fj[0].x * WQK[0];
            float qb = fj[0].y * WQK[0];
            #pragma unroll
            for (int j = 1; j < 8; ++j) {
                qa = fmaf(fj[j].x, WQK[j], qa);
                qb = fmaf(fj[j].y, WQK[j], qb);
            }
            #pragma unroll
            for (int d = 1; d <= 16; d <<= 1) {
                qa += __shfl_xor(qa, d);
                qb += __shfl_xor(qb, d);
            }
            const float ra = fmaxf(qa + kreg, 0.f);
            const float rb = fmaxf(qb + kreg, 0.f);
            if ((t & 31) == 0) {
                atomicAdd(&sn[n], ra);
                atomicAdd(&sn[n + 1], rb);
            }
        }

        __syncthreads();   // B2: sn complete

        // ---- aggregation: thread (c, j=i) builds F0..F5 over neighbors ----
        float F0 = 0.f, F1 = 0.f, F2 = 0.f, F3 = 0.f, F4 = 0.f, F5 = 0.f;
        float ssum = 0.f;
        #pragma unroll
        for (int n2 = 0; n2 < 8; ++n2) {
            const int n = 2 * n2;
            const float sca = 0.125f * sn[n] * smask[n];
            const float scb = 0.125f * sn[n + 1] * smask[n + 1];
            const float u0a = rpu[(size_t)(vq + n) * 2];
            const float u1a = rpu[(size_t)(vq + n) * 2 + 1];
            const float u0b = rpu[(size_t)(vq + n + 1) * 2];
            const float u1b = rpu[(size_t)(vq + n + 1) * 2 + 1];
            const float2 fp = *(const float2*)&fsh2[i][c][n];
            ssum += sca + scb;
            const float fsa = fp.x * sca;
            const float fsb = fp.y * scb;
            F0 += fsa + fsb;
            F1 = fmaf(u0a, fsa, fmaf(u0b, fsb, F1));
            F2 = fmaf(u1a, fsa, fmaf(u1b, fsb, F2));
            F3 = fmaf(u0a * u0a, fsa, fmaf(u0b * u0b, fsb, F3));
            F4 = fmaf(2.f * u0a * u1a, fsa, fmaf(2.f * u0b * u1b, fsb, F4));
            F5 = fmaf(u1a * u1a, fsa, fmaf(u1b * u1b, fsb, F5));
        }
        *(float2*)&Fsh[i][c][0] = make_float2(F0, F1);
        *(float2*)&Fsh[i][c][2] = make_float2(F2, F3);
        *(float2*)&Fsh[i][c][4] = make_float2(F4, F5);

        __syncthreads();   // B3: Fsh complete

        // ---- final: out[c,i] = sum_j sum_k WV[k*8+j] * Fk[c,j] ----
        float a0 = 0.f, a1 = 0.f, a2 = 0.f;
        #pragma unroll
        for (int jj = 0; jj < 8; ++jj) {
            const float2 F01 = *(const float2*)&Fsh[jj][c][0];
            const float2 F23 = *(const float2*)&Fsh[jj][c][2];
            const float2 F45 = *(const float2*)&Fsh[jj][c][4];
            a0 = fmaf(WV[     jj], F01.x, a0);
            a1 = fmaf(WV[ 8 + jj], F01.y, a1);
            a2 = fmaf(WV[16 + jj], F23.x, a2);
            a0 = fmaf(WV[24 + jj], F23.y, a0);
            a1 = fmaf(WV[32 + jj], F45.x, a1);
            a2 = fmaf(WV[40 + jj], F45.y, a2);
        }
        out[(size_t)v * 256 + c * 8 + i] = (a0 + a1 + a2) / fmaxf(ssum, 1e-8f);
        // loop hazards: next-iter fsh2/sn/smask writes are pre-B1' while all
        // reads of this iter completed pre-B3; Fsh written only post-B2'.
    }
}

extern "C" void kernel_launch(void* const* d_in, const int* in_sizes, int n_in,
                              void* d_out, int out_size, void* d_ws, size_t ws_size,
                              hipStream_t stream) {
    const float* x         = (const float*)d_in[0];
    const int*   neighbors = (const int*)d_in[1];
    const void*  maskp     = d_in[2];
    const float* ptm       = (const float*)d_in[3];
    const float* rpu       = (const float*)d_in[4];
    const float* rr        = (const float*)d_in[5];
    const float* vb0       = (const float*)d_in[6];
    const float* vb1       = (const float*)d_in[7];
    const float* vb2       = (const float*)d_in[8];
    const float* qc        = (const float*)d_in[9];
    const float* kc        = (const float*)d_in[10];
    const float* w0p       = (const float*)d_in[11];
    const float* w1p       = (const float*)d_in[12];
    const float* w2p       = (const float*)d_in[13];
    float* out = (float*)d_out;

    int*    flag = (int*)d_ws;
    float4* wtab = (float4*)((char*)d_ws + 1024);   // 64KB table

    detect_mask_kind<<<1, 64, 0, stream>>>((const unsigned int*)maskp, flag);
    compute_weights<<<1, 256, 0, stream>>>(rr, vb0, vb1, vb2,
                                           qc, kc, w0p, w1p, w2p, wtab);
    ge_attn_kernel<<<NBLK, 256, 0, stream>>>(x, neighbors, maskp, ptm, rpu,
                                             wtab, flag, out);
}

// Round 15
// 301.946 us; speedup vs baseline: 1.0832x; 1.0832x over previous
//
#include <hip/hip_runtime.h>

#define NV   20000
#define MAXN 16

// ---------------------------------------------------------------------------
// Mask dtype detection (bool may arrive as int32 / byte / float32).
// ---------------------------------------------------------------------------
__global__ void detect_mask_kind(const unsigned int* __restrict__ m,
                                 int* __restrict__ flag) {
    if (threadIdx.x == 0 && blockIdx.x == 0) {
        int allint = 1, allflt = 1;
        #pragma unroll 8
        for (int k = 0; k < 64; ++k) {
            unsigned w = m[k];
            if (!(w == 0u || w == 1u)) allint = 0;
            if (!(w == 0u || w == 0x3F800000u)) allflt = 0;
        }
        *flag = allint ? 0 : (allflt ? 2 : 1);
    }
}

// ---------------------------------------------------------------------------
// One-time weight combine: per thread slot t=(c,i), 8 rows of 8
// (WQ, WK, W0, W1o0, W1o1, W2o0, W2o1, W2o2) = 16 float4 contiguous per t.
// ---------------------------------------------------------------------------
__global__ void compute_weights(const float* __restrict__ rr,
                                const float* __restrict__ vb0,
                                const float* __restrict__ vb1,
                                const float* __restrict__ vb2,
                                const float* __restrict__ qc,
                                const float* __restrict__ kc,
                                const float* __restrict__ w0p,
                                const float* __restrict__ w1p,
                                const float* __restrict__ w2p,
                                float4* __restrict__ wt) {
    const int t = threadIdx.x;
    const int c = t & 31;
    const int i = t >> 5;
    float WQr[8], WKr[8], W0r[8], W1r0[8], W1r1[8], W2r0[8], W2r1[8], W2r2[8];
    #pragma unroll
    for (int j = 0; j < 8; ++j) {
        WQr[j] = 0.f; WKr[j] = 0.f; W0r[j] = 0.f; W1r0[j] = 0.f;
        W1r1[j] = 0.f; W2r0[j] = 0.f; W2r1[j] = 0.f; W2r2[j] = 0.f;
    }
    #pragma unroll
    for (int b = 0; b < 8; ++b) {
        const float qcb = qc[c * 8 + b];
        const float kcb = kc[c * 8 + b];
        const float w0b = w0p[c * 8 + b];
        const float w1b = w1p[c * 8 + b];
        const float w2b = w2p[c * 8 + b];
        const float* rrb = rr  + b * 64  + i * 8;
        const float* z0  = vb0 + b * 64  + i * 8;
        const float* z1  = vb1 + b * 128 + i * 8;   // [b][o][i][j]
        const float* z2  = vb2 + b * 192 + i * 8;
        #pragma unroll
        for (int j = 0; j < 8; ++j) {
            const float r = rrb[j];
            WQr[j]  = fmaf(qcb, r, WQr[j]);
            WKr[j]  = fmaf(kcb, r, WKr[j]);
            W0r[j]  = fmaf(w0b, z0[j],       W0r[j]);
            W1r0[j] = fmaf(w1b, z1[j],       W1r0[j]);
            W1r1[j] = fmaf(w1b, z1[64 + j],  W1r1[j]);
            W2r0[j] = fmaf(w2b, z2[j],       W2r0[j]);
            W2r1[j] = fmaf(w2b, z2[64 + j],  W2r1[j]);
            W2r2[j] = fmaf(w2b, z2[128 + j], W2r2[j]);
        }
    }
    float4* o = wt + t * 16;
    o[ 0] = *(const float4*)&WQr[0];  o[ 1] = *(const float4*)&WQr[4];
    o[ 2] = *(const float4*)&WKr[0];  o[ 3] = *(const float4*)&WKr[4];
    o[ 4] = *(const float4*)&W0r[0];  o[ 5] = *(const float4*)&W0r[4];
    o[ 6] = *(const float4*)&W1r0[0]; o[ 7] = *(const float4*)&W1r0[4];
    o[ 8] = *(const float4*)&W1r1[0]; o[ 9] = *(const float4*)&W1r1[4];
    o[10] = *(const float4*)&W2r0[0]; o[11] = *(const float4*)&W2r0[4];
    o[12] = *(const float4*)&W2r1[0]; o[13] = *(const float4*)&W2r1[4];
    o[14] = *(const float4*)&W2r2[0]; o[15] = *(const float4*)&W2r2[4];
}

__device__ __forceinline__ float dot8a(const float* __restrict__ w,
                                       const float* __restrict__ f) {
    float s = w[0] * f[0];
    #pragma unroll
    for (int j = 1; j < 8; ++j) s = fmaf(w[j], f[j], s);
    return s;
}

__device__ __forceinline__ float dot8f4(const float4& a, const float4& b,
                                        const float* __restrict__ f) {
    return fmaf(a.x, f[0], fmaf(a.y, f[1], fmaf(a.z, f[2], fmaf(a.w, f[3],
           fmaf(b.x, f[4], fmaf(b.y, f[5], fmaf(b.z, f[6], b.w * f[7])))))));
}

// R13 base (291us, zero spills) + two low-pressure cuts:
//  (a) sqni stage removed: Q[n,i] reduces fully in one 32-lane half
//      (depth-5 shfl; kreg=K[i] thread-local) -> relu -> 1 atomic into sn.
//      Barriers 4 -> 3; no zeroing/fixup/kk.
//  (b) fsh layout [n][c][10] (j-contiguous): pass-A reads 4xb64/neighbor
//      (was 8xb32), phase-1 writes 4xb64 (was 8xb32). 10c mod 32 -> 2-way
//      bank alias = free. NOT bundled: R14's whole-loop WV pin (spilled) and
//      stride-18 (4-way conflicts). WV load placement identical to R13.
__global__ void __launch_bounds__(256, 5)
ge_attn_kernel(const float* __restrict__ x,
               const int*   __restrict__ neighbors,
               const void*  __restrict__ maskp,
               const float* __restrict__ ptm,
               const float* __restrict__ rpu,
               const float4* __restrict__ wt,
               const int*   __restrict__ mflag,
               float*       __restrict__ out) {
    const int t = threadIdx.x;
    const int c = t & 31;   // channel
    const int i = t >> 5;   // rep index (also j-slot in aggregation)
    const int mf = *mflag;

    __shared__ float fsh[16][32][10];  // f' [n][c][j(0..7)+pad2]  20.5KB
    __shared__ float Fsh[8][32][6];    // aggregated features [j][c][k] 6KB
    __shared__ float sn[16];           // sum_i relu(Q+K)
    __shared__ float smask[16];

    const int v  = blockIdx.x;
    const int vq = v * 16;

    // mask -> LDS; zero sn (consumed after B1)
    if (t < 16) {
        int mm;
        if (mf == 0)      mm = (((const int*)maskp)[vq + t] != 0);
        else if (mf == 1) mm = (((const unsigned char*)maskp)[vq + t] != 0);
        else              mm = (((const float*)maskp)[vq + t] != 0.0f);
        smask[t] = mm ? 1.f : 0.f;
    } else if (t < 32) {
        sn[t - 16] = 0.f;
    }

    // WQ/WK rows (16 floats pinned); WV loaded after pass A (R13 placement)
    float WQK[16];
    {
        const float4* wp = wt + t * 16;
        #pragma unroll
        for (int r = 0; r < 4; ++r) {
            const float4 q = wp[r];
            WQK[r * 4 + 0] = q.x; WQK[r * 4 + 1] = q.y;
            WQK[r * 4 + 2] = q.z; WQK[r * 4 + 3] = q.w;
        }
        #pragma unroll
        for (int r = 0; r < 16; ++r)
            asm volatile("" : "+v"(WQK[r]));
    }

    // ---- phase 1: transport n=2i,2i+1 (mask-scaled) -> fsh[n][c][:] ----
    #pragma unroll
    for (int sub = 0; sub < 2; ++sub) {
        const int n = 2 * i + sub;
        int mm;
        if (mf == 0)      mm = (((const int*)maskp)[vq + n] != 0);
        else if (mf == 1) mm = (((const unsigned char*)maskp)[vq + n] != 0);
        else              mm = (((const float*)maskp)[vq + n] != 0.0f);
        const float m = mm ? 1.f : 0.f;
        const int nbv = neighbors[vq + n];
        float xn[8];
        {
            const float* xnp = x + (size_t)nbv * 256 + c * 8;
            *(float4*)&xn[0] = *(const float4*)xnp;
            *(float4*)&xn[4] = *(const float4*)(xnp + 4);
        }
        const float4* P4 = (const float4*)(ptm + (size_t)(vq + n) * 64);
        #pragma unroll
        for (int j2 = 0; j2 < 4; ++j2) {
            float2 fo;
            fo.x = dot8f4(P4[4 * j2 + 0], P4[4 * j2 + 1], xn) * m;
            fo.y = dot8f4(P4[4 * j2 + 2], P4[4 * j2 + 3], xn) * m;
            *(float2*)&fsh[n][c][2 * j2] = fo;   // 8B-aligned (40c+8j2)
        }
    }

    // K[i]: in-half reduction, kept in register by every lane
    float kreg;
    {
        float xc[8];
        const float* xv = x + (size_t)v * 256 + c * 8;
        *(float4*)&xc[0] = *(const float4*)xv;
        *(float4*)&xc[4] = *(const float4*)(xv + 4);
        float kp = dot8a(&WQK[8], xc);
        kp += __shfl_xor(kp, 1);
        kp += __shfl_xor(kp, 2);
        kp += __shfl_xor(kp, 4);
        kp += __shfl_xor(kp, 8);
        kp += __shfl_xor(kp, 16);
        kreg = kp;
    }

    __syncthreads();   // B1: fsh, smask, sn=0

    // ---- pass A: Q[n,i] full in-half reduction, relu, direct sn atomic ----
    #pragma unroll
    for (int n2 = 0; n2 < 8; ++n2) {
        const int n = 2 * n2;
        float fa[8], fb[8];
        #pragma unroll
        for (int j2 = 0; j2 < 4; ++j2) {
            *(float2*)&fa[2 * j2] = *(const float2*)&fsh[n][c][2 * j2];
            *(float2*)&fb[2 * j2] = *(const float2*)&fsh[n + 1][c][2 * j2];
        }
        float qa = dot8a(&WQK[0], fa);
        float qb = dot8a(&WQK[0], fb);
        #pragma unroll
        for (int d = 1; d <= 16; d <<= 1) {
            qa += __shfl_xor(qa, d);
            qb += __shfl_xor(qb, d);
        }
        const float ra = fmaxf(qa + kreg, 0.f);
        const float rb = fmaxf(qb + kreg, 0.f);
        if ((t & 31) == 0) {
            atomicAdd(&sn[n], ra);
            atomicAdd(&sn[n + 1], rb);
        }
    }

    // issue value-row loads now; consumed only in the final dots
    float WV[48];
    {
        const float4* wp = wt + t * 16 + 4;
        #pragma unroll
        for (int r = 0; r < 12; ++r) {
            const float4 q = wp[r];
            WV[r * 4 + 0] = q.x; WV[r * 4 + 1] = q.y;
            WV[r * 4 + 2] = q.z; WV[r * 4 + 3] = q.w;
        }
    }

    __syncthreads();   // B2: sn complete

    // ---- aggregation: thread (c, j=i) builds F0..F5[c,j] over neighbors ----
    float F0 = 0.f, F1 = 0.f, F2 = 0.f, F3 = 0.f, F4 = 0.f, F5 = 0.f;
    float ssum = 0.f;
    #pragma unroll
    for (int n2 = 0; n2 < 8; ++n2) {
        const int n = 2 * n2;
        const float sca = 0.125f * sn[n] * smask[n];
        const float scb = 0.125f * sn[n + 1] * smask[n + 1];
        const float2 ua = *(const float2*)&rpu[(size_t)(vq + n) * 2];
        const float2 ub = *(const float2*)&rpu[(size_t)(vq + n + 1) * 2];
        const float fa = fsh[n][c][i];
        const float fb = fsh[n + 1][c][i];
        ssum += sca + scb;
        const float fsa = fa * sca;
        const float fsb = fb * scb;
        F0 += fsa + fsb;
        F1 = fmaf(ua.x, fsa, fmaf(ub.x, fsb, F1));
        F2 = fmaf(ua.y, fsa, fmaf(ub.y, fsb, F2));
        F3 = fmaf(ua.x * ua.x, fsa, fmaf(ub.x * ub.x, fsb, F3));
        F4 = fmaf(2.f * ua.x * ua.y, fsa, fmaf(2.f * ub.x * ub.y, fsb, F4));
        F5 = fmaf(ua.y * ua.y, fsa, fmaf(ub.y * ub.y, fsb, F5));
    }
    *(float2*)&Fsh[i][c][0] = make_float2(F0, F1);
    *(float2*)&Fsh[i][c][2] = make_float2(F2, F3);
    *(float2*)&Fsh[i][c][4] = make_float2(F4, F5);

    __syncthreads();   // B3: Fsh complete

    #pragma unroll
    for (int r = 0; r < 48; ++r)
        asm volatile("" : "+v"(WV[r]));   // pin value rows for the final dots

    // ---- final: out[c,i] = sum_j sum_k WV[k*8+j] * Fk[c,j], / denom ----
    float a0 = 0.f, a1 = 0.f, a2 = 0.f;
    #pragma unroll
    for (int jj = 0; jj < 8; ++jj) {
        const float2 F01 = *(const float2*)&Fsh[jj][c][0];
        const float2 F23 = *(const float2*)&Fsh[jj][c][2];
        const float2 F45 = *(const float2*)&Fsh[jj][c][4];
        a0 = fmaf(WV[     jj], F01.x, a0);
        a1 = fmaf(WV[ 8 + jj], F01.y, a1);
        a2 = fmaf(WV[16 + jj], F23.x, a2);
        a0 = fmaf(WV[24 + jj], F23.y, a0);
        a1 = fmaf(WV[32 + jj], F45.x, a1);
        a2 = fmaf(WV[40 + jj], F45.y, a2);
    }
    out[(size_t)v * 256 + c * 8 + i] = (a0 + a1 + a2) / fmaxf(ssum, 1e-8f);
}

extern "C" void kernel_launch(void* const* d_in, const int* in_sizes, int n_in,
                              void* d_out, int out_size, void* d_ws, size_t ws_size,
                              hipStream_t stream) {
    const float* x         = (const float*)d_in[0];
    const int*   neighbors = (const int*)d_in[1];
    const void*  maskp     = d_in[2];
    const float* ptm       = (const float*)d_in[3];
    const float* rpu       = (const float*)d_in[4];
    const float* rr        = (const float*)d_in[5];
    const float* vb0       = (const float*)d_in[6];
    const float* vb1       = (const float*)d_in[7];
    const float* vb2       = (const float*)d_in[8];
    const float* qc        = (const float*)d_in[9];
    const float* kc        = (const float*)d_in[10];
    const float* w0p       = (const float*)d_in[11];
    const float* w1p       = (const float*)d_in[12];
    const float* w2p       = (const float*)d_in[13];
    float* out = (float*)d_out;

    int*    flag = (int*)d_ws;
    float4* wtab = (float4*)((char*)d_ws + 1024);   // 64KB table

    detect_mask_kind<<<1, 64, 0, stream>>>((const unsigned int*)maskp, flag);
    compute_weights<<<1, 256, 0, stream>>>(rr, vb0, vb1, vb2,
                                           qc, kc, w0p, w1p, w2p, wtab);
    ge_attn_kernel<<<NV, 256, 0, stream>>>(x, neighbors, maskp, ptm, rpu,
                                           wtab, flag, out);
}

// Round 16
// 289.310 us; speedup vs baseline: 1.1305x; 1.0437x over previous
//
#include <hip/hip_runtime.h>

#define NV   20000
#define MAXN 16

// ---------------------------------------------------------------------------
// Mask dtype detection (bool may arrive as int32 / byte / float32).
// ---------------------------------------------------------------------------
__global__ void detect_mask_kind(const unsigned int* __restrict__ m,
                                 int* __restrict__ flag) {
    if (threadIdx.x == 0 && blockIdx.x == 0) {
        int allint = 1, allflt = 1;
        #pragma unroll 8
        for (int k = 0; k < 64; ++k) {
            unsigned w = m[k];
            if (!(w == 0u || w == 1u)) allint = 0;
            if (!(w == 0u || w == 0x3F800000u)) allflt = 0;
        }
        *flag = allint ? 0 : (allflt ? 2 : 1);
    }
}

// ---------------------------------------------------------------------------
// One-time weight combine: per thread slot t=(c,i), 8 rows of 8
// (WQ, WK, W0, W1o0, W1o1, W2o0, W2o1, W2o2) = 16 float4 contiguous per t.
// ---------------------------------------------------------------------------
__global__ void compute_weights(const float* __restrict__ rr,
                                const float* __restrict__ vb0,
                                const float* __restrict__ vb1,
                                const float* __restrict__ vb2,
                                const float* __restrict__ qc,
                                const float* __restrict__ kc,
                                const float* __restrict__ w0p,
                                const float* __restrict__ w1p,
                                const float* __restrict__ w2p,
                                float4* __restrict__ wt) {
    const int t = threadIdx.x;
    const int c = t & 31;
    const int i = t >> 5;
    float WQr[8], WKr[8], W0r[8], W1r0[8], W1r1[8], W2r0[8], W2r1[8], W2r2[8];
    #pragma unroll
    for (int j = 0; j < 8; ++j) {
        WQr[j] = 0.f; WKr[j] = 0.f; W0r[j] = 0.f; W1r0[j] = 0.f;
        W1r1[j] = 0.f; W2r0[j] = 0.f; W2r1[j] = 0.f; W2r2[j] = 0.f;
    }
    #pragma unroll
    for (int b = 0; b < 8; ++b) {
        const float qcb = qc[c * 8 + b];
        const float kcb = kc[c * 8 + b];
        const float w0b = w0p[c * 8 + b];
        const float w1b = w1p[c * 8 + b];
        const float w2b = w2p[c * 8 + b];
        const float* rrb = rr  + b * 64  + i * 8;
        const float* z0  = vb0 + b * 64  + i * 8;
        const float* z1  = vb1 + b * 128 + i * 8;   // [b][o][i][j]
        const float* z2  = vb2 + b * 192 + i * 8;
        #pragma unroll
        for (int j = 0; j < 8; ++j) {
            const float r = rrb[j];
            WQr[j]  = fmaf(qcb, r, WQr[j]);
            WKr[j]  = fmaf(kcb, r, WKr[j]);
            W0r[j]  = fmaf(w0b, z0[j],       W0r[j]);
            W1r0[j] = fmaf(w1b, z1[j],       W1r0[j]);
            W1r1[j] = fmaf(w1b, z1[64 + j],  W1r1[j]);
            W2r0[j] = fmaf(w2b, z2[j],       W2r0[j]);
            W2r1[j] = fmaf(w2b, z2[64 + j],  W2r1[j]);
            W2r2[j] = fmaf(w2b, z2[128 + j], W2r2[j]);
        }
    }
    float4* o = wt + t * 16;
    o[ 0] = *(const float4*)&WQr[0];  o[ 1] = *(const float4*)&WQr[4];
    o[ 2] = *(const float4*)&WKr[0];  o[ 3] = *(const float4*)&WKr[4];
    o[ 4] = *(const float4*)&W0r[0];  o[ 5] = *(const float4*)&W0r[4];
    o[ 6] = *(const float4*)&W1r0[0]; o[ 7] = *(const float4*)&W1r0[4];
    o[ 8] = *(const float4*)&W1r1[0]; o[ 9] = *(const float4*)&W1r1[4];
    o[10] = *(const float4*)&W2r0[0]; o[11] = *(const float4*)&W2r0[4];
    o[12] = *(const float4*)&W2r1[0]; o[13] = *(const float4*)&W2r1[4];
    o[14] = *(const float4*)&W2r2[0]; o[15] = *(const float4*)&W2r2[4];
}

__device__ __forceinline__ float dot8a(const float* __restrict__ w,
                                       const float* __restrict__ f) {
    float s = w[0] * f[0];
    #pragma unroll
    for (int j = 1; j < 8; ++j) s = fmaf(w[j], f[j], s);
    return s;
}

__device__ __forceinline__ float dot8f4(const float4& a, const float4& b,
                                        const float* __restrict__ f) {
    return fmaf(a.x, f[0], fmaf(a.y, f[1], fmaf(a.z, f[2], fmaf(a.w, f[3],
           fmaf(b.x, f[4], fmaf(b.y, f[5], fmaf(b.z, f[6], b.w * f[7])))))));
}

// R13 base (291us, zero spills) with ONE structural change: the WV value
// rows are no longer asm-pinned. In R13 the 48 pinned floats lived in AGPRs
// (unified regfile: 48 VGPR + 64 AGPR ~ 112 regs -> 4 waves/SIMD, the real
// occupancy cap at 55%). WV is consumed exactly ONCE (48 FMA epilogue), so
// R5's reload-in-loop pathology cannot recur: load it at the use site.
// launch_bounds 5 -> 6 (cap ~85 regs; est peak ~73) to claim the freed slots.
__global__ void __launch_bounds__(256, 6)
ge_attn_kernel(const float* __restrict__ x,
               const int*   __restrict__ neighbors,
               const void*  __restrict__ maskp,
               const float* __restrict__ ptm,
               const float* __restrict__ rpu,
               const float4* __restrict__ wt,
               const int*   __restrict__ mflag,
               float*       __restrict__ out) {
    const int t = threadIdx.x;
    const int c = t & 31;   // channel
    const int i = t >> 5;   // rep index (also the j-slot in aggregation)
    const int mf = *mflag;

    // f' store: [j][c][n], stride-17 pad -> conflict-free for both the
    // pass-A (c,i) reads and the aggregation (c,j) reads.  17.4KB
    __shared__ float fsh2[8][32][17];
    __shared__ float Fsh[8][32][6];   // aggregated features [j][c][k]  6KB
    __shared__ float sqni[16][8];     // Q[n,i] accumulators (pre-relu)
    __shared__ float kk[8];           // K[i]
    __shared__ float sn[16];          // sum_i relu(Q+K)
    __shared__ float smask[16];

    const int v  = blockIdx.x;
    const int vq = v * 16;

    // zero accumulators; mask -> LDS
    if (t < 128) ((float*)sqni)[t] = 0.f;
    else if (t < 144) sn[t - 128] = 0.f;
    if (t < 16) {
        int mm;
        if (mf == 0)      mm = (((const int*)maskp)[vq + t] != 0);
        else if (mf == 1) mm = (((const unsigned char*)maskp)[vq + t] != 0);
        else              mm = (((const float*)maskp)[vq + t] != 0.0f);
        smask[t] = mm ? 1.f : 0.f;
    }

    // WQ/WK rows (16 floats pinned)
    float WQK[16];
    {
        const float4* wp = wt + t * 16;
        #pragma unroll
        for (int r = 0; r < 4; ++r) {
            const float4 q = wp[r];
            WQK[r * 4 + 0] = q.x; WQK[r * 4 + 1] = q.y;
            WQK[r * 4 + 2] = q.z; WQK[r * 4 + 3] = q.w;
        }
        #pragma unroll
        for (int r = 0; r < 16; ++r)
            asm volatile("" : "+v"(WQK[r]));
    }

    // ---- phase 1: transport n=2i,2i+1 (mask-scaled), scatter to fsh2 ----
    #pragma unroll
    for (int sub = 0; sub < 2; ++sub) {
        const int n = 2 * i + sub;
        int mm;
        if (mf == 0)      mm = (((const int*)maskp)[vq + n] != 0);
        else if (mf == 1) mm = (((const unsigned char*)maskp)[vq + n] != 0);
        else              mm = (((const float*)maskp)[vq + n] != 0.0f);
        const float m = mm ? 1.f : 0.f;
        const int nbv = neighbors[vq + n];
        float xn[8];
        {
            const float* xnp = x + (size_t)nbv * 256 + c * 8;
            *(float4*)&xn[0] = *(const float4*)xnp;
            *(float4*)&xn[4] = *(const float4*)(xnp + 4);
        }
        const float4* P4 = (const float4*)(ptm + (size_t)(vq + n) * 64);
        #pragma unroll
        for (int j2 = 0; j2 < 4; ++j2) {
            fsh2[2 * j2    ][c][n] = dot8f4(P4[4 * j2 + 0], P4[4 * j2 + 1], xn) * m;
            fsh2[2 * j2 + 1][c][n] = dot8f4(P4[4 * j2 + 2], P4[4 * j2 + 3], xn) * m;
        }
    }

    // K[i]: one shuffle reduction per vertex
    {
        float xc[8];
        const float* xv = x + (size_t)v * 256 + c * 8;
        *(float4*)&xc[0] = *(const float4*)xv;
        *(float4*)&xc[4] = *(const float4*)(xv + 4);
        float kp = dot8a(&WQK[8], xc);
        kp += __shfl_xor(kp, 1);
        kp += __shfl_xor(kp, 2);
        kp += __shfl_xor(kp, 4);
        kp += __shfl_xor(kp, 8);
        kp += __shfl_xor(kp, 16);
        if ((t & 31) == 0) kk[i] = kp;
    }

    __syncthreads();   // B1

    // ---- pass A: Q[n,i] partials, neighbor pairs for ILP ----
    #pragma unroll 2
    for (int n2 = 0; n2 < 8; ++n2) {
        const int n = 2 * n2;
        float fa[8], fb[8];
        #pragma unroll
        for (int j = 0; j < 8; ++j) {
            fa[j] = fsh2[j][c][n];
            fb[j] = fsh2[j][c][n + 1];
        }
        float qa = dot8a(&WQK[0], fa);
        float qb = dot8a(&WQK[0], fb);
        qa += __shfl_xor(qa, 1);  qb += __shfl_xor(qb, 1);
        qa += __shfl_xor(qa, 2);  qb += __shfl_xor(qb, 2);
        qa += __shfl_xor(qa, 4);  qb += __shfl_xor(qb, 4);
        if ((c & 7) == 0) {
            atomicAdd(&sqni[n][i], qa);
            atomicAdd(&sqni[n + 1][i], qb);
        }
    }

    __syncthreads();   // B2: sqni done

    if (t < 128) {
        const int nn = t >> 3, ii = t & 7;
        atomicAdd(&sn[nn], fmaxf(sqni[nn][ii] + kk[ii], 0.f));
    }

    __syncthreads();   // B3: sn done

    // ---- aggregation: thread (c, j=i) builds F0..F5[c,j] over neighbors ----
    float F0 = 0.f, F1 = 0.f, F2 = 0.f, F3 = 0.f, F4 = 0.f, F5 = 0.f;
    float ssum = 0.f;
    #pragma unroll 4
    for (int n2 = 0; n2 < 8; ++n2) {
        const int n = 2 * n2;
        const float sca = 0.125f * sn[n] * smask[n];
        const float scb = 0.125f * sn[n + 1] * smask[n + 1];
        const float u0a = rpu[(size_t)(vq + n) * 2];
        const float u1a = rpu[(size_t)(vq + n) * 2 + 1];
        const float u0b = rpu[(size_t)(vq + n + 1) * 2];
        const float u1b = rpu[(size_t)(vq + n + 1) * 2 + 1];
        const float fa = fsh2[i][c][n];
        const float fb = fsh2[i][c][n + 1];
        ssum += sca + scb;
        const float fsa = fa * sca;
        const float fsb = fb * scb;
        F0 += fsa + fsb;
        F1 = fmaf(u0a, fsa, fmaf(u0b, fsb, F1));
        F2 = fmaf(u1a, fsa, fmaf(u1b, fsb, F2));
        F3 = fmaf(u0a * u0a, fsa, fmaf(u0b * u0b, fsb, F3));
        F4 = fmaf(2.f * u0a * u1a, fsa, fmaf(2.f * u0b * u1b, fsb, F4));
        F5 = fmaf(u1a * u1a, fsa, fmaf(u1b * u1b, fsb, F5));
    }
    *(float2*)&Fsh[i][c][0] = make_float2(F0, F1);
    *(float2*)&Fsh[i][c][2] = make_float2(F2, F3);
    *(float2*)&Fsh[i][c][4] = make_float2(F4, F5);

    __syncthreads();   // B4: Fsh done

    // ---- final: load WV at the single use site (unpinned), contract ----
    float WV[48];
    {
        const float4* wp = wt + t * 16 + 4;
        #pragma unroll
        for (int r = 0; r < 12; ++r) {
            const float4 q = wp[r];
            WV[r * 4 + 0] = q.x; WV[r * 4 + 1] = q.y;
            WV[r * 4 + 2] = q.z; WV[r * 4 + 3] = q.w;
        }
    }
    float a0 = 0.f, a1 = 0.f, a2 = 0.f;
    #pragma unroll
    for (int jj = 0; jj < 8; ++jj) {
        const float2 F01 = *(const float2*)&Fsh[jj][c][0];
        const float2 F23 = *(const float2*)&Fsh[jj][c][2];
        const float2 F45 = *(const float2*)&Fsh[jj][c][4];
        a0 = fmaf(WV[     jj], F01.x, a0);
        a1 = fmaf(WV[ 8 + jj], F01.y, a1);
        a2 = fmaf(WV[16 + jj], F23.x, a2);
        a0 = fmaf(WV[24 + jj], F23.y, a0);
        a1 = fmaf(WV[32 + jj], F45.x, a1);
        a2 = fmaf(WV[40 + jj], F45.y, a2);
    }
    const float acc = a0 + a1 + a2;
    out[(size_t)v * 256 + c * 8 + i] = acc / fmaxf(ssum, 1e-8f);
}

extern "C" void kernel_launch(void* const* d_in, const int* in_sizes, int n_in,
                              void* d_out, int out_size, void* d_ws, size_t ws_size,
                              hipStream_t stream) {
    const float* x         = (const float*)d_in[0];
    const int*   neighbors = (const int*)d_in[1];
    const void*  maskp     = d_in[2];
    const float* ptm       = (const float*)d_in[3];
    const float* rpu       = (const float*)d_in[4];
    const float* rr        = (const float*)d_in[5];
    const float* vb0       = (const float*)d_in[6];
    const float* vb1       = (const float*)d_in[7];
    const float* vb2       = (const float*)d_in[8];
    const float* qc        = (const float*)d_in[9];
    const float* kc        = (const float*)d_in[10];
    const float* w0p       = (const float*)d_in[11];
    const float* w1p       = (const float*)d_in[12];
    const float* w2p       = (const float*)d_in[13];
    float* out = (float*)d_out;

    int*    flag = (int*)d_ws;
    float4* wtab = (float4*)((char*)d_ws + 1024);   // 64KB table

    detect_mask_kind<<<1, 64, 0, stream>>>((const unsigned int*)maskp, flag);
    compute_weights<<<1, 256, 0, stream>>>(rr, vb0, vb1, vb2,
                                           qc, kc, w0p, w1p, w2p, wtab);
    ge_attn_kernel<<<NV, 256, 0, stream>>>(x, neighbors, maskp, ptm, rpu,
                                           wtab, flag, out);
}